// Round 12
// baseline (659.466 us; speedup 1.0000x reference)
//
#include <hip/hip_runtime.h>
#include <hip/hip_fp16.h>
#include <math.h>

// ---------------------------------------------------------------------------
// Sender model, MI355X, round 12.
// All GEMMs on fp16x2 (Markidis) MFMA: 3 products, fp32 accumulate.
// logits: B-STATIONARY chunked GEMM. Wave holds its 32-col Wo panel (K=256,
// both splits) in 128 VGPRs, loaded once. Block loops 16 chunks of 32 h-rows;
// only the A-chunk (32 KB) is staged per barrier (double-buffered, stage
// issued BEFORE compute). 96 MFMA/wave per barrier (2x R8), softmax stats
// fused per-chunk with cross-wave LDS merge -> pstats = 32 panels (4 MB).
// K1/K2 + skeleton reverted to the proven R8 form.
// ---------------------------------------------------------------------------

typedef __attribute__((ext_vector_type(8))) _Float16 half8v;  // 16 B
typedef __attribute__((ext_vector_type(4))) float f32x4;

// slot swizzle for K1/K2 (R8 form); row stride 64 B
__device__ __forceinline__ int lds_off(int row, int slot) {
    return (row << 6) + ((slot ^ (row & 3) ^ ((row >> 2) & 3)) << 4);
}

__device__ __forceinline__ void gld_lds16(const void* src, void* dst) {
    __builtin_amdgcn_global_load_lds(
        (const __attribute__((address_space(1))) void*)src,
        (__attribute__((address_space(3))) void*)dst, 16, 0, 0);
}

template<int C>
__device__ __forceinline__ float dppf(float x) {
    return __builtin_bit_cast(float, __builtin_amdgcn_update_dpp(
        __builtin_bit_cast(int, x), __builtin_bit_cast(int, x), C, 0xF, 0xF, false));
}
template<int C>
__device__ __forceinline__ int dppi(int x) {
    return __builtin_amdgcn_update_dpp(x, x, C, 0xF, 0xF, false);
}

__device__ __forceinline__ void f16split(float v, unsigned short& u0,
                                         unsigned short& u1) {
    __half a = __float2half(v);            // RTNE
    float f = __half2float(a);
    __half b = __float2half(v - f);
    u0 = __half_as_ushort(a);
    u1 = __half_as_ushort(b);
}

__device__ __forceinline__ float fast_tanh(float x) {
    float t = __expf(-2.0f * fabsf(x));    // t in (0,1], no overflow
    float th = (1.0f - t) / (1.0f + t);
    return copysignf(th, x);
}

// ---------------- elementwise fp16x2 split (vis) ----------------------------
__global__ __launch_bounds__(256) void split_ew(
    const float* __restrict__ in, unsigned short* __restrict__ o0,
    unsigned short* __restrict__ o1, int n4)
{
    int i = blockIdx.x * 256 + threadIdx.x;
    if (i >= n4) return;
    float4 v = *(const float4*)&in[(size_t)i * 4];
    unsigned short a[4], b[4];
    f16split(v.x, a[0], b[0]); f16split(v.y, a[1], b[1]);
    f16split(v.z, a[2], b[2]); f16split(v.w, a[3], b[3]);
    *(uint2*)&o0[(size_t)i * 4] = *(uint2*)a;
    *(uint2*)&o1[(size_t)i * 4] = *(uint2*)b;
}

// ---------------- W[K][N] -> [n][k] fp16x2 splits (Wo, Wv, grk) -------------
__global__ __launch_bounds__(256) void trans_split(
    const float* __restrict__ W, unsigned short* __restrict__ o0,
    unsigned short* __restrict__ o1, int N, int K)
{
    __shared__ float Ts[64][65];
    const int tid = threadIdx.x;
    const int n0 = blockIdx.x * 64, k0 = blockIdx.y * 64;
    const int ty = tid >> 2, tx = tid & 3;
    #pragma unroll
    for (int q = 0; q < 4; ++q) {
        float4 v = *(const float4*)&W[(size_t)(k0 + ty) * N + n0 + tx * 16 + q * 4];
        Ts[ty][tx * 16 + q * 4 + 0] = v.x; Ts[ty][tx * 16 + q * 4 + 1] = v.y;
        Ts[ty][tx * 16 + q * 4 + 2] = v.z; Ts[ty][tx * 16 + q * 4 + 3] = v.w;
    }
    __syncthreads();
    #pragma unroll
    for (int ii = 0; ii < 2; ++ii) {
        int item = tid + (ii << 8);          // 0..511
        int n = item >> 3, g = item & 7;     // n 0..63, k-group 0..7
        unsigned short u0[8], u1[8];
        #pragma unroll
        for (int e = 0; e < 8; ++e)
            f16split(Ts[g * 8 + e][n], u0[e], u1[e]);
        size_t base = (size_t)(n0 + n) * K + k0 + g * 8;
        *(uint4*)&o0[base] = *(uint4*)u0;
        *(uint4*)&o1[base] = *(uint4*)u1;
    }
}

// ---------------- fp16x2 MFMA GEMM, 64x64 tile (K1, K2) -- R8 form ----------
template<int KTOT, bool SPLIT>
__global__ __launch_bounds__(256) void mfma_gemm(
    const unsigned short* __restrict__ a0s, const unsigned short* __restrict__ a1s,
    const unsigned short* __restrict__ b0s, const unsigned short* __restrict__ b1s,
    const float* __restrict__ bias, float* __restrict__ C, int ldc,
    unsigned short* __restrict__ s0, unsigned short* __restrict__ s1)
{
    __shared__ char lds[16384];
    const int tid = threadIdx.x;
    const int w = tid >> 6, lane = tid & 63;
    const int c16 = lane & 15, rg = lane >> 4;
    const int m0 = blockIdx.y << 6, n0 = blockIdx.x << 6;
    const int arow0 = (w >> 1) << 5, brow0 = (w & 1) << 5;

    const unsigned short* segsrc = (w == 0) ? a0s : (w == 1) ? a1s
                                 : (w == 2) ? b0s : b1s;
    const int segrow0 = (w < 2) ? m0 : n0;

    f32x4 acc[2][2] = {};

    for (int t = 0; t < KTOT / 32; ++t) {
        const int k0 = t << 5;
        #pragma unroll
        for (int q = 0; q < 4; ++q) {
            int row = (q << 4) + (lane >> 2);
            int slot = (lane & 3) ^ (row & 3) ^ ((row >> 2) & 3);
            gld_lds16(segsrc + (size_t)(segrow0 + row) * KTOT + k0 + (slot << 3),
                      &lds[(w << 12) + (q << 10)]);
        }
        asm volatile("s_waitcnt vmcnt(0)" ::: "memory");
        __syncthreads();
        half8v afr[2][2], bfr[2][2];
        #pragma unroll
        for (int i = 0; i < 2; ++i) {
            int oa = lds_off(arow0 + (i << 4) + c16, rg);
            afr[i][0] = *(half8v*)&lds[oa];
            afr[i][1] = *(half8v*)&lds[4096 + oa];
            int ob = lds_off(brow0 + (i << 4) + c16, rg);
            bfr[i][0] = *(half8v*)&lds[8192 + ob];
            bfr[i][1] = *(half8v*)&lds[12288 + ob];
        }
        #pragma unroll
        for (int i = 0; i < 2; ++i)
            #pragma unroll
            for (int j = 0; j < 2; ++j) {
                f32x4 c = acc[i][j];
                c = __builtin_amdgcn_mfma_f32_16x16x32_f16(afr[i][0], bfr[j][0], c, 0, 0, 0);
                c = __builtin_amdgcn_mfma_f32_16x16x32_f16(afr[i][1], bfr[j][0], c, 0, 0, 0);
                c = __builtin_amdgcn_mfma_f32_16x16x32_f16(afr[i][0], bfr[j][1], c, 0, 0, 0);
                acc[i][j] = c;
            }
        __syncthreads();
    }

    #pragma unroll
    for (int j = 0; j < 2; ++j) {
        int col = n0 + brow0 + (j << 4) + c16;
        float bb = bias[col];
        #pragma unroll
        for (int i = 0; i < 2; ++i)
            #pragma unroll
            for (int reg = 0; reg < 4; ++reg) {
                int row = m0 + arow0 + (i << 4) + (rg << 2) + reg;
                float v = acc[i][j][reg] + bb;
                C[(size_t)row * ldc + col] = v;
                if (SPLIT) {
                    unsigned short u0, u1;
                    f16split(v, u0, u1);
                    s0[(size_t)row * ldc + col] = u0;
                    s1[(size_t)row * ldc + col] = u1;
                }
            }
    }
}

// ---------------- gru_fused: merge(t-1, 32 panels) + GRU + h split ----------
__global__ __launch_bounds__(256) void gru_fused(
    const float4* __restrict__ pstats, const float* __restrict__ emb,
    const float* __restrict__ gk, const float* __restrict__ b_in,
    const float* __restrict__ hm, const float* __restrict__ ph,
    unsigned short* __restrict__ h0, unsigned short* __restrict__ h1,
    float* __restrict__ ht_out, float* __restrict__ out_seq,
    float* __restrict__ out_sel, float* __restrict__ out_ent, int t)
{
    __shared__ float xsT[64][8];
    __shared__ int syms_lds[8];
    const int tid = threadIdx.x;
    const int row0 = blockIdx.x * 8;
    float az[8], ar[8], ah[8];
    const float bz = b_in[tid], br = b_in[256 + tid], bh = b_in[512 + tid];
    #pragma unroll
    for (int r = 0; r < 8; ++r) { az[r] = bz; ar[r] = br; ah[r] = bh; }

    if (t > 0) {
        const int r = tid >> 5, p = tid & 31;
        const int row = row0 + r;
        float4 pa = pstats[(size_t)p * 8192 + row];
        float M = pa.x, S = pa.y, Q = pa.z;
        int A = __float_as_int(pa.w);
        #pragma unroll
        for (int off = 1; off < 32; off <<= 1) {
            float m2 = __shfl_xor(M, off);
            float s2 = __shfl_xor(S, off);
            float q2 = __shfl_xor(Q, off);
            int   a2 = __shfl_xor(A, off);
            S += s2; Q += q2;
            if (m2 > M || (m2 == M && a2 < A)) { M = m2; A = a2; }
        }
        if (p == 0) {
            float lse = __logf(S);
            float sel = M - lse;
            float ent = lse - Q / S;
            out_seq[(size_t)row * 6 + (t - 1)] = (float)A;
            out_sel[(size_t)row * 6 + (t - 1)] = sel;
            float ea = (t == 1) ? ent : (out_ent[row] + ent);
            out_ent[row] = ea;
            syms_lds[r] = A;
        }
        __syncthreads();
        for (int l = tid; l < 512; l += 256) {
            int r2 = l >> 6, e = l & 63;
            xsT[e][r2] = emb[(size_t)syms_lds[r2] * 64 + e];
        }
        __syncthreads();
        #pragma unroll 4
        for (int e = 0; e < 64; ++e) {
            float kz  = gk[e * 768 + tid];
            float kr_ = gk[e * 768 + 256 + tid];
            float kh  = gk[e * 768 + 512 + tid];
            float4 x0 = *(float4*)&xsT[e][0];
            float4 x1 = *(float4*)&xsT[e][4];
            float xv[8] = {x0.x, x0.y, x0.z, x0.w, x1.x, x1.y, x1.z, x1.w};
            #pragma unroll
            for (int r2 = 0; r2 < 8; ++r2) {
                az[r2] = fmaf(xv[r2], kz, az[r2]);
                ar[r2] = fmaf(xv[r2], kr_, ar[r2]);
                ah[r2] = fmaf(xv[r2], kh, ah[r2]);
            }
        }
    }
    #pragma unroll
    for (int r = 0; r < 8; ++r) {
        const int row = row0 + r;
        float hz  = hm[(size_t)row * 768 + tid];
        float hr  = hm[(size_t)row * 768 + 256 + tid];
        float hh  = hm[(size_t)row * 768 + 512 + tid];
        float phv = ph[(size_t)row * 256 + tid];
        float z  = 1.0f / (1.0f + __expf(-(az[r] + hz)));
        float rr = 1.0f / (1.0f + __expf(-(ar[r] + hr)));
        float ht = fast_tanh(ah[r] + rr * hh);
        float hv = z * phv + (1.0f - z) * ht;
        size_t idx = (size_t)row * 256 + tid;
        unsigned short u0, u1;
        f16split(hv, u0, u1);
        h0[idx] = u0; h1[idx] = u1;
        if (ht_out) ht_out[idx] = hv;
    }
}

// ---------------- logits: B-stationary chunked fp16x2 MFMA ------------------
// Grid (16 mstrips, 32 npanels); block 256 thr / 4 waves; wave owns 32 cols
// with B-frags (2 nfrag x 8 kstep x 2 splits = 128 VGPR) register-resident.
// 16 chunks of 32 rows; A-chunk (32 KB) double-buffered in LDS, frag-major;
// stage of chunk c+1 issued before compute of chunk c. Stats fused per chunk,
// cross-wave merged via LDS scratch -> pstats[32 panels][8192].
__global__ __launch_bounds__(256, 2) void logits_mfma(
    const unsigned short* __restrict__ h0, const unsigned short* __restrict__ h1,
    const unsigned short* __restrict__ w0, const unsigned short* __restrict__ w1,
    const float* __restrict__ bo, float4* __restrict__ pstats)
{
    __shared__ char lds[67584];            // 2 x 32 KB staging + 2 KB scratch
    const int tid = threadIdx.x;
    const int w = tid >> 6, lane = tid & 63;
    const int c16 = lane & 15, rg = lane >> 4;
    const int strip_row0 = blockIdx.x << 9;     // 16 strips x 512 rows
    const int npanel = blockIdx.y;              // 32 panels x 128 cols
    const int cols0 = (npanel << 7) + (w << 5); // wave's 32 cols

    // ---- B-resident: 2 nfrags x 8 ksteps x 2 splits = 32 frags -------------
    half8v B0[8][2], B1[8][2];
    {
        size_t b0 = (size_t)(cols0 + c16) * 256 + rg * 8;
        size_t b1 = (size_t)(cols0 + 16 + c16) * 256 + rg * 8;
        #pragma unroll
        for (int t = 0; t < 8; ++t) {
            B0[t][0] = *(const half8v*)(w0 + b0 + t * 32);
            B0[t][1] = *(const half8v*)(w0 + b1 + t * 32);
            B1[t][0] = *(const half8v*)(w1 + b0 + t * 32);
            B1[t][1] = *(const half8v*)(w1 + b1 + t * 32);
        }
    }
    const float bv0 = bo[cols0 + c16];
    const float bv1 = bo[cols0 + 16 + c16];

    // staging: wave w -> split s=w>>1, ksteps (w&1)*4..+3, both mfrags.
    const unsigned short* hs = (w < 2) ? h0 : h1;
    const int tb = (w & 1) << 2;
    const int sseg = (w >> 1) << 14;           // 0 or 16384

    #define STAGE(c_, buf_) {                                                  \
        const int r0_ = strip_row0 + ((c_) << 5);                              \
        _Pragma("unroll")                                                      \
        for (int u = 0; u < 8; ++u) {                                          \
            const int tt = tb + (u >> 1), ii = u & 1;                          \
            gld_lds16(hs + (size_t)(r0_ + ii * 16 + c16) * 256 + tt * 32 + rg * 8, \
                      &lds[((buf_) << 15) + sseg + ((tt * 2 + ii) << 10)]);    \
        } }

    STAGE(0, 0)
    asm volatile("s_waitcnt vmcnt(0)" ::: "memory");
    __syncthreads();

    const int lb = lane << 4;
    for (int c = 0; c < 16; ++c) {
        if (c < 15) STAGE(c + 1, (c + 1) & 1)   // prefetch next chunk
        const int base = (c & 1) << 15;

        f32x4 acc[2][2] = {};
        #pragma unroll
        for (int t = 0; t < 8; ++t) {
            half8v a00 = *(half8v*)&lds[base + ((t * 2 + 0) << 10) + lb];
            half8v a01 = *(half8v*)&lds[base + ((t * 2 + 1) << 10) + lb];
            half8v a10 = *(half8v*)&lds[base + 16384 + ((t * 2 + 0) << 10) + lb];
            half8v a11 = *(half8v*)&lds[base + 16384 + ((t * 2 + 1) << 10) + lb];
            f32x4 c00 = acc[0][0], c01 = acc[0][1], c10 = acc[1][0], c11 = acc[1][1];
            c00 = __builtin_amdgcn_mfma_f32_16x16x32_f16(a00, B0[t][0], c00, 0, 0, 0);
            c01 = __builtin_amdgcn_mfma_f32_16x16x32_f16(a00, B0[t][1], c01, 0, 0, 0);
            c10 = __builtin_amdgcn_mfma_f32_16x16x32_f16(a01, B0[t][0], c10, 0, 0, 0);
            c11 = __builtin_amdgcn_mfma_f32_16x16x32_f16(a01, B0[t][1], c11, 0, 0, 0);
            c00 = __builtin_amdgcn_mfma_f32_16x16x32_f16(a10, B0[t][0], c00, 0, 0, 0);
            c01 = __builtin_amdgcn_mfma_f32_16x16x32_f16(a10, B0[t][1], c01, 0, 0, 0);
            c10 = __builtin_amdgcn_mfma_f32_16x16x32_f16(a11, B0[t][0], c10, 0, 0, 0);
            c11 = __builtin_amdgcn_mfma_f32_16x16x32_f16(a11, B0[t][1], c11, 0, 0, 0);
            c00 = __builtin_amdgcn_mfma_f32_16x16x32_f16(a00, B1[t][0], c00, 0, 0, 0);
            c01 = __builtin_amdgcn_mfma_f32_16x16x32_f16(a00, B1[t][1], c01, 0, 0, 0);
            c10 = __builtin_amdgcn_mfma_f32_16x16x32_f16(a01, B1[t][0], c10, 0, 0, 0);
            c11 = __builtin_amdgcn_mfma_f32_16x16x32_f16(a01, B1[t][1], c11, 0, 0, 0);
            acc[0][0] = c00; acc[0][1] = c01; acc[1][0] = c10; acc[1][1] = c11;
        }

        // per-wave stats over this wave's 32 cols, rows of chunk c
        #pragma unroll
        for (int i = 0; i < 2; ++i) {
            #pragma unroll
            for (int reg = 0; reg < 4; ++reg) {
                float l0 = acc[i][0][reg] + bv0;
                float l1 = acc[i][1][reg] + bv1;
                float m; int a;
                if (l1 > l0) { m = l1; a = cols0 + 16 + c16; }
                else         { m = l0; a = cols0 + c16; }
                float e0 = __expf(l0), e1 = __expf(l1);
                float s = e0 + e1;
                float q = fmaf(l0, e0, l1 * e1);
                s += dppf<0x108>(s); s += dppf<0x104>(s);
                s += dppf<0x102>(s); s += dppf<0x101>(s);
                q += dppf<0x108>(q); q += dppf<0x104>(q);
                q += dppf<0x102>(q); q += dppf<0x101>(q);
                #define MMERGE(C) { float m2 = dppf<C>(m); int a2 = dppi<C>(a); \
                    bool bt = (m2 > m) || (m2 == m && a2 < a); \
                    m = bt ? m2 : m; a = bt ? a2 : a; }
                MMERGE(0x108) MMERGE(0x104) MMERGE(0x102) MMERGE(0x101)
                #undef MMERGE
                if (c16 == 0) {
                    int r_in = i * 16 + (rg << 2) + reg;      // 0..31
                    *(float4*)&lds[65536 + (((w << 5) + r_in) << 4)] =
                        make_float4(m, s, q, __int_as_float(a));
                }
            }
        }
        __syncthreads();                       // scratch ready; buf[c] reads done
        if (tid < 32) {                        // merge 4 waves (cols ascending)
            float4 p0 = *(float4*)&lds[65536 + (tid << 4)];
            float4 p1 = *(float4*)&lds[65536 + ((32 + tid) << 4)];
            float4 p2 = *(float4*)&lds[65536 + ((64 + tid) << 4)];
            float4 p3 = *(float4*)&lds[65536 + ((96 + tid) << 4)];
            float M = p0.x, S = p0.y, Q = p0.z; int A = __float_as_int(p0.w);
            S += p1.y + p2.y + p3.y;
            Q += p1.z + p2.z + p3.z;
            { int a2 = __float_as_int(p1.w);
              if (p1.x > M || (p1.x == M && a2 < A)) { M = p1.x; A = a2; } }
            { int a2 = __float_as_int(p2.w);
              if (p2.x > M || (p2.x == M && a2 < A)) { M = p2.x; A = a2; } }
            { int a2 = __float_as_int(p3.w);
              if (p3.x > M || (p3.x == M && a2 < A)) { M = p3.x; A = a2; } }
            pstats[(size_t)npanel * 8192 + strip_row0 + (c << 5) + tid] =
                make_float4(M, S, Q, __int_as_float(A));
        }
        asm volatile("s_waitcnt vmcnt(0)" ::: "memory");   // next buf staged
        __syncthreads();
    }
    #undef STAGE
}

// ---------------- final finalize: merge t=5 (32 panels), close outputs ------
__global__ __launch_bounds__(64) void finalize_kernel(
    const float4* __restrict__ pstats, float* __restrict__ out_seq,
    float* __restrict__ out_sel, float* __restrict__ out_ent,
    float* __restrict__ out_ml)
{
    const int row = blockIdx.x * 64 + threadIdx.x;
    float M = -INFINITY, S = 0.f, Q = 0.f; int A = 0;
    #pragma unroll 8
    for (int p = 0; p < 32; ++p) {
        float4 pp = pstats[(size_t)p * 8192 + row];
        S += pp.y; Q += pp.z;
        int a2 = __float_as_int(pp.w);
        if (pp.x > M || (pp.x == M && a2 < A)) { M = pp.x; A = a2; }
    }
    float lse = __logf(S);
    float sel = M - lse;
    float ent = lse - Q / S;
    out_seq[(size_t)row * 6 + 5] = (float)A;
    out_sel[(size_t)row * 6 + 5] = sel;
    out_ent[row] = (out_ent[row] + ent) * (1.0f / 6.0f);
    out_ml[row] = 6.0f;
}

// ---------------------------------------------------------------------------
extern "C" void kernel_launch(void* const* d_in, const int* in_sizes, int n_in,
                              void* d_out, int out_size, void* d_ws, size_t ws_size,
                              hipStream_t stream) {
    const float* vis  = (const float*)d_in[0];
    const float* Wv   = (const float*)d_in[1];
    const float* bv   = (const float*)d_in[2];
    const float* gk   = (const float*)d_in[3];
    const float* grk  = (const float*)d_in[4];
    const float* bin  = (const float*)d_in[5];
    const float* brec = (const float*)d_in[6];
    const float* Wo   = (const float*)d_in[7];
    const float* bo   = (const float*)d_in[8];
    const float* emb  = (const float*)d_in[9];

    float* out = (float*)d_out;
    float* out_seq = out;                 // (8192, 6)
    float* out_sel = out + 49152;         // (8192, 6)
    float* out_ent = out + 98304;         // (8192,)
    float* out_ml  = out + 106496;        // (8192,)
    float* out_ht  = out + 114688;        // (8192, 256)

    char* ws = (char*)d_ws;
    float*          ph     = (float*)(ws);                       // 8 MB
    float*          hm     = (float*)(ws + 8388608);             // 24 MB
    unsigned short* vis0   = (unsigned short*)(ws + 8388608);    // 8 MB (overlay hm; dead before K2)
    unsigned short* vis1   = (unsigned short*)(ws + 16777216);   // 8 MB (overlay hm)
    unsigned short* h0     = (unsigned short*)(ws + 33554432);   // 4 MB
    unsigned short* h1     = (unsigned short*)(ws + 37748736);   // 4 MB
    unsigned short* w0     = (unsigned short*)(ws + 41943040);   // 2 MB
    unsigned short* w1     = (unsigned short*)(ws + 44040192);   // 2 MB
    float4*         pstats = (float4*)(ws + 46137344);           // 4 MB (32 panels)
    unsigned short* ph0    = (unsigned short*)(ws + 46137344);   // 4 MB (overlay pstats; dead before first logits)
    unsigned short* ph1    = (unsigned short*)(ws + 50331648);   // 4 MB
    unsigned short* wv0    = (unsigned short*)(ws + 54558720);   // 256 KB
    unsigned short* wv1    = (unsigned short*)(ws + 54820864);   // 256 KB
    unsigned short* g0     = (unsigned short*)(ws + 55083008);   // 384 KB
    unsigned short* g1     = (unsigned short*)(ws + 55476224);   // 384 KB

    // one-time weight preps (loop-invariant)
    trans_split<<<dim3(64, 4), 256, 0, stream>>>(Wo, w0, w1, 4096, 256);
    trans_split<<<dim3(4, 8), 256, 0, stream>>>(Wv, wv0, wv1, 256, 512);
    trans_split<<<dim3(12, 4), 256, 0, stream>>>(grk, g0, g1, 768, 256);
    split_ew<<<4096, 256, 0, stream>>>(vis, vis0, vis1, 1048576);

    // K1: prev_hidden = vis @ Wv + bv (epilogue also emits ph0/ph1 splits)
    mfma_gemm<512, true><<<dim3(4, 128), 256, 0, stream>>>(
        vis0, vis1, wv0, wv1, bv, ph, 256, ph0, ph1);
    // K2: hm = prev_hidden @ grk + brec (loop-invariant)
    mfma_gemm<256, false><<<dim3(12, 128), 256, 0, stream>>>(
        ph0, ph1, g0, g1, brec, hm, 768, nullptr, nullptr);

    for (int t = 0; t < 6; ++t) {
        gru_fused<<<1024, 256, 0, stream>>>(pstats, emb, gk, bin, hm, ph,
                                            h0, h1,
                                            (t == 5) ? out_ht : nullptr,
                                            out_seq, out_sel, out_ent, t);
        logits_mfma<<<dim3(16, 32), 256, 0, stream>>>(h0, h1, w0, w1, bo, pstats);
    }
    finalize_kernel<<<128, 64, 0, stream>>>(pstats, out_seq, out_sel,
                                            out_ent, out_ml);
}

// Round 13
// 556.934 us; speedup vs baseline: 1.1841x; 1.1841x over previous
//
#include <hip/hip_runtime.h>
#include <hip/hip_fp16.h>
#include <math.h>

// ---------------------------------------------------------------------------
// Sender model, MI355X, round 13 == best-known configuration (R8) restored.
// All GEMMs on fp16x2 (Markidis) MFMA: 3 products, fp32 accumulate.
// logits: 128x128 tile, slot-swizzled LDS, single 32 KB buffer, vmcnt(0)+
// __syncthreads per K-step, launch_bounds(256,3). Proven 67 us/dispatch.
// R9-R12 lessons: reg-dbuf (137us), counted-vmcnt (73us), frag-major (84us),
// B-stationary (93us) -- all regress vs this form. Micro-opts kept from R9:
// fast_tanh / __logf / __expf (absmax unchanged across rounds).
// ---------------------------------------------------------------------------

typedef __attribute__((ext_vector_type(8))) _Float16 half8v;  // 16 B
typedef __attribute__((ext_vector_type(4))) float f32x4;

// slot swizzle; row stride 64 B
__device__ __forceinline__ int lds_off(int row, int slot) {
    return (row << 6) + ((slot ^ (row & 3) ^ ((row >> 2) & 3)) << 4);
}

__device__ __forceinline__ void gld_lds16(const void* src, void* dst) {
    __builtin_amdgcn_global_load_lds(
        (const __attribute__((address_space(1))) void*)src,
        (__attribute__((address_space(3))) void*)dst, 16, 0, 0);
}

template<int C>
__device__ __forceinline__ float dppf(float x) {
    return __builtin_bit_cast(float, __builtin_amdgcn_update_dpp(
        __builtin_bit_cast(int, x), __builtin_bit_cast(int, x), C, 0xF, 0xF, false));
}
template<int C>
__device__ __forceinline__ int dppi(int x) {
    return __builtin_amdgcn_update_dpp(x, x, C, 0xF, 0xF, false);
}

__device__ __forceinline__ void f16split(float v, unsigned short& u0,
                                         unsigned short& u1) {
    __half a = __float2half(v);            // RTNE
    float f = __half2float(a);
    __half b = __float2half(v - f);
    u0 = __half_as_ushort(a);
    u1 = __half_as_ushort(b);
}

__device__ __forceinline__ float fast_tanh(float x) {
    float t = __expf(-2.0f * fabsf(x));    // t in (0,1], no overflow
    float th = (1.0f - t) / (1.0f + t);
    return copysignf(th, x);
}

// ---------------- elementwise fp16x2 split (vis) ----------------------------
__global__ __launch_bounds__(256) void split_ew(
    const float* __restrict__ in, unsigned short* __restrict__ o0,
    unsigned short* __restrict__ o1, int n4)
{
    int i = blockIdx.x * 256 + threadIdx.x;
    if (i >= n4) return;
    float4 v = *(const float4*)&in[(size_t)i * 4];
    unsigned short a[4], b[4];
    f16split(v.x, a[0], b[0]); f16split(v.y, a[1], b[1]);
    f16split(v.z, a[2], b[2]); f16split(v.w, a[3], b[3]);
    *(uint2*)&o0[(size_t)i * 4] = *(uint2*)a;
    *(uint2*)&o1[(size_t)i * 4] = *(uint2*)b;
}

// ---------------- W[K][N] -> [n][k] fp16x2 splits (Wo, Wv, grk) -------------
__global__ __launch_bounds__(256) void trans_split(
    const float* __restrict__ W, unsigned short* __restrict__ o0,
    unsigned short* __restrict__ o1, int N, int K)
{
    __shared__ float Ts[64][65];
    const int tid = threadIdx.x;
    const int n0 = blockIdx.x * 64, k0 = blockIdx.y * 64;
    const int ty = tid >> 2, tx = tid & 3;
    #pragma unroll
    for (int q = 0; q < 4; ++q) {
        float4 v = *(const float4*)&W[(size_t)(k0 + ty) * N + n0 + tx * 16 + q * 4];
        Ts[ty][tx * 16 + q * 4 + 0] = v.x; Ts[ty][tx * 16 + q * 4 + 1] = v.y;
        Ts[ty][tx * 16 + q * 4 + 2] = v.z; Ts[ty][tx * 16 + q * 4 + 3] = v.w;
    }
    __syncthreads();
    #pragma unroll
    for (int ii = 0; ii < 2; ++ii) {
        int item = tid + (ii << 8);          // 0..511
        int n = item >> 3, g = item & 7;     // n 0..63, k-group 0..7
        unsigned short u0[8], u1[8];
        #pragma unroll
        for (int e = 0; e < 8; ++e)
            f16split(Ts[g * 8 + e][n], u0[e], u1[e]);
        size_t base = (size_t)(n0 + n) * K + k0 + g * 8;
        *(uint4*)&o0[base] = *(uint4*)u0;
        *(uint4*)&o1[base] = *(uint4*)u1;
    }
}

// ---------------- fp16x2 MFMA GEMM, 64x64 tile (K1, K2) ---------------------
// 4 waves (2x2), wave tile 32x32 = 2x2 frags of 16x16x32 f16, 3 products.
// Single-buffer 16 KB LDS. SPLIT: also emit fp16x2 split of C (K1 -> ph0/ph1).
template<int KTOT, bool SPLIT>
__global__ __launch_bounds__(256) void mfma_gemm(
    const unsigned short* __restrict__ a0s, const unsigned short* __restrict__ a1s,
    const unsigned short* __restrict__ b0s, const unsigned short* __restrict__ b1s,
    const float* __restrict__ bias, float* __restrict__ C, int ldc,
    unsigned short* __restrict__ s0, unsigned short* __restrict__ s1)
{
    __shared__ char lds[16384];
    const int tid = threadIdx.x;
    const int w = tid >> 6, lane = tid & 63;
    const int c16 = lane & 15, rg = lane >> 4;
    const int m0 = blockIdx.y << 6, n0 = blockIdx.x << 6;
    const int arow0 = (w >> 1) << 5, brow0 = (w & 1) << 5;

    const unsigned short* segsrc = (w == 0) ? a0s : (w == 1) ? a1s
                                 : (w == 2) ? b0s : b1s;
    const int segrow0 = (w < 2) ? m0 : n0;

    f32x4 acc[2][2] = {};

    for (int t = 0; t < KTOT / 32; ++t) {
        const int k0 = t << 5;
        #pragma unroll
        for (int q = 0; q < 4; ++q) {
            int row = (q << 4) + (lane >> 2);
            int slot = (lane & 3) ^ (row & 3) ^ ((row >> 2) & 3);
            gld_lds16(segsrc + (size_t)(segrow0 + row) * KTOT + k0 + (slot << 3),
                      &lds[(w << 12) + (q << 10)]);
        }
        asm volatile("s_waitcnt vmcnt(0)" ::: "memory");
        __syncthreads();
        half8v afr[2][2], bfr[2][2];
        #pragma unroll
        for (int i = 0; i < 2; ++i) {
            int oa = lds_off(arow0 + (i << 4) + c16, rg);
            afr[i][0] = *(half8v*)&lds[oa];
            afr[i][1] = *(half8v*)&lds[4096 + oa];
            int ob = lds_off(brow0 + (i << 4) + c16, rg);
            bfr[i][0] = *(half8v*)&lds[8192 + ob];
            bfr[i][1] = *(half8v*)&lds[12288 + ob];
        }
        #pragma unroll
        for (int i = 0; i < 2; ++i)
            #pragma unroll
            for (int j = 0; j < 2; ++j) {
                f32x4 c = acc[i][j];
                c = __builtin_amdgcn_mfma_f32_16x16x32_f16(afr[i][0], bfr[j][0], c, 0, 0, 0);
                c = __builtin_amdgcn_mfma_f32_16x16x32_f16(afr[i][1], bfr[j][0], c, 0, 0, 0);
                c = __builtin_amdgcn_mfma_f32_16x16x32_f16(afr[i][0], bfr[j][1], c, 0, 0, 0);
                acc[i][j] = c;
            }
        __syncthreads();
    }

    #pragma unroll
    for (int j = 0; j < 2; ++j) {
        int col = n0 + brow0 + (j << 4) + c16;
        float bb = bias[col];
        #pragma unroll
        for (int i = 0; i < 2; ++i)
            #pragma unroll
            for (int reg = 0; reg < 4; ++reg) {
                int row = m0 + arow0 + (i << 4) + (rg << 2) + reg;
                float v = acc[i][j][reg] + bb;
                C[(size_t)row * ldc + col] = v;
                if (SPLIT) {
                    unsigned short u0, u1;
                    f16split(v, u0, u1);
                    s0[(size_t)row * ldc + col] = u0;
                    s1[(size_t)row * ldc + col] = u1;
                }
            }
    }
}

// ---------------- gru_fused: merge(t-1) + emb gather + GRU + h split --------
// 8 rows/block. t>0: merge step t-1's 64 pstats panels for these rows,
// write outputs for t-1, keep syms in LDS for the emb gather.
__global__ __launch_bounds__(256) void gru_fused(
    const float4* __restrict__ pstats, const float* __restrict__ emb,
    const float* __restrict__ gk, const float* __restrict__ b_in,
    const float* __restrict__ hm, const float* __restrict__ ph,
    unsigned short* __restrict__ h0, unsigned short* __restrict__ h1,
    float* __restrict__ ht_out, float* __restrict__ out_seq,
    float* __restrict__ out_sel, float* __restrict__ out_ent, int t)
{
    __shared__ float xsT[64][8];
    __shared__ int syms_lds[8];
    const int tid = threadIdx.x;
    const int row0 = blockIdx.x * 8;
    float az[8], ar[8], ah[8];
    const float bz = b_in[tid], br = b_in[256 + tid], bh = b_in[512 + tid];
    #pragma unroll
    for (int r = 0; r < 8; ++r) { az[r] = bz; ar[r] = br; ah[r] = bh; }

    if (t > 0) {
        const int r = tid >> 5, p = tid & 31;
        const int row = row0 + r;
        float4 pa = pstats[(size_t)p * 8192 + row];
        float4 pb = pstats[(size_t)(p + 32) * 8192 + row];
        float M = pa.x, S = pa.y + pb.y, Q = pa.z + pb.z;
        int A = __float_as_int(pa.w);
        { int a2 = __float_as_int(pb.w);
          if (pb.x > M || (pb.x == M && a2 < A)) { M = pb.x; A = a2; } }
        #pragma unroll
        for (int off = 1; off < 32; off <<= 1) {
            float m2 = __shfl_xor(M, off);
            float s2 = __shfl_xor(S, off);
            float q2 = __shfl_xor(Q, off);
            int   a2 = __shfl_xor(A, off);
            S += s2; Q += q2;
            if (m2 > M || (m2 == M && a2 < A)) { M = m2; A = a2; }
        }
        if (p == 0) {
            float lse = __logf(S);
            float sel = M - lse;
            float ent = lse - Q / S;
            out_seq[(size_t)row * 6 + (t - 1)] = (float)A;
            out_sel[(size_t)row * 6 + (t - 1)] = sel;
            float ea = (t == 1) ? ent : (out_ent[row] + ent);
            out_ent[row] = ea;
            syms_lds[r] = A;
        }
        __syncthreads();
        for (int l = tid; l < 512; l += 256) {
            int r2 = l >> 6, e = l & 63;
            xsT[e][r2] = emb[(size_t)syms_lds[r2] * 64 + e];
        }
        __syncthreads();
        #pragma unroll 4
        for (int e = 0; e < 64; ++e) {
            float kz  = gk[e * 768 + tid];
            float kr_ = gk[e * 768 + 256 + tid];
            float kh  = gk[e * 768 + 512 + tid];
            float4 x0 = *(float4*)&xsT[e][0];
            float4 x1 = *(float4*)&xsT[e][4];
            float xv[8] = {x0.x, x0.y, x0.z, x0.w, x1.x, x1.y, x1.z, x1.w};
            #pragma unroll
            for (int r2 = 0; r2 < 8; ++r2) {
                az[r2] = fmaf(xv[r2], kz, az[r2]);
                ar[r2] = fmaf(xv[r2], kr_, ar[r2]);
                ah[r2] = fmaf(xv[r2], kh, ah[r2]);
            }
        }
    }
    #pragma unroll
    for (int r = 0; r < 8; ++r) {
        const int row = row0 + r;
        float hz  = hm[(size_t)row * 768 + tid];
        float hr  = hm[(size_t)row * 768 + 256 + tid];
        float hh  = hm[(size_t)row * 768 + 512 + tid];
        float phv = ph[(size_t)row * 256 + tid];
        float z  = 1.0f / (1.0f + __expf(-(az[r] + hz)));
        float rr = 1.0f / (1.0f + __expf(-(ar[r] + hr)));
        float ht = fast_tanh(ah[r] + rr * hh);
        float hv = z * phv + (1.0f - z) * ht;
        size_t idx = (size_t)row * 256 + tid;
        unsigned short u0, u1;
        f16split(hv, u0, u1);
        h0[idx] = u0; h1[idx] = u1;
        if (ht_out) ht_out[idx] = hv;
    }
}

// ---------------- logits: 128x128 fp16x2 MFMA, single-buf 32 KB -------------
// 4 waves (2x2), wave tile 64x64 = 4x4 frags of 16x16x32 f16, 3 products.
// launch_bounds(256,3): reg budget ~170 >= ~152 needed -> no spill; 3 blk/CU.
__global__ __launch_bounds__(256, 3) void logits_mfma(
    const unsigned short* __restrict__ h0, const unsigned short* __restrict__ h1,
    const unsigned short* __restrict__ w0, const unsigned short* __restrict__ w1,
    const float* __restrict__ bo, float4* __restrict__ pstats)
{
    __shared__ char lds[32768];
    const int tid = threadIdx.x;
    const int w = tid >> 6, lane = tid & 63;
    const int c16 = lane & 15, rg = lane >> 4;
    const int m0 = blockIdx.y << 7, n0 = blockIdx.x << 7;
    const int arow0 = (w >> 1) << 6, brow0 = (w & 1) << 6;

    const unsigned short* segsrc = (w == 0) ? h0 : (w == 1) ? h1
                                 : (w == 2) ? w0 : w1;
    const int segrow0 = (w < 2) ? m0 : n0;

    f32x4 acc[4][4] = {};

    for (int t = 0; t < 8; ++t) {
        const int k0 = t << 5;
        #pragma unroll
        for (int q = 0; q < 8; ++q) {          // stage this K-step (own segment)
            int row = (q << 4) + (lane >> 2);
            int slot = (lane & 3) ^ (row & 3) ^ ((row >> 2) & 3);
            gld_lds16(segsrc + (size_t)(segrow0 + row) * 256 + k0 + (slot << 3),
                      &lds[(w << 13) + (q << 10)]);
        }
        asm volatile("s_waitcnt vmcnt(0)" ::: "memory");
        __syncthreads();
        half8v afr[4][2];
        #pragma unroll
        for (int i = 0; i < 4; ++i) {
            int o = lds_off(arow0 + (i << 4) + c16, rg);
            afr[i][0] = *(half8v*)&lds[o];
            afr[i][1] = *(half8v*)&lds[8192 + o];
        }
        #pragma unroll
        for (int j = 0; j < 4; ++j) {
            int o = lds_off(brow0 + (j << 4) + c16, rg);
            half8v b0 = *(half8v*)&lds[16384 + o];
            half8v b1 = *(half8v*)&lds[24576 + o];
            #pragma unroll
            for (int i = 0; i < 4; ++i) {
                f32x4 c = acc[i][j];
                c = __builtin_amdgcn_mfma_f32_16x16x32_f16(afr[i][0], b0, c, 0, 0, 0);
                c = __builtin_amdgcn_mfma_f32_16x16x32_f16(afr[i][1], b0, c, 0, 0, 0);
                c = __builtin_amdgcn_mfma_f32_16x16x32_f16(afr[i][0], b1, c, 0, 0, 0);
                acc[i][j] = c;
            }
        }
        __syncthreads();
    }

    // epilogue: raw softmax stats (logits bounded -> no max shift),
    // DPP row_shl reductions across the 16 c16 lanes.
    const int wn0 = n0 + brow0;
    float bov[4];
    #pragma unroll
    for (int j = 0; j < 4; ++j) bov[j] = bo[wn0 + j * 16 + c16];
    #pragma unroll
    for (int i = 0; i < 4; ++i) {
        #pragma unroll
        for (int reg = 0; reg < 4; ++reg) {
            float l0 = acc[i][0][reg] + bov[0];
            float l1 = acc[i][1][reg] + bov[1];
            float l2 = acc[i][2][reg] + bov[2];
            float l3 = acc[i][3][reg] + bov[3];
            float m = l0; int a = wn0 + c16;
            if (l1 > m) { m = l1; a = wn0 + 16 + c16; }
            if (l2 > m) { m = l2; a = wn0 + 32 + c16; }
            if (l3 > m) { m = l3; a = wn0 + 48 + c16; }
            float e0 = __expf(l0), e1 = __expf(l1), e2 = __expf(l2), e3 = __expf(l3);
            float s = (e0 + e1) + (e2 + e3);
            float q = fmaf(l0, e0, fmaf(l1, e1, fmaf(l2, e2, l3 * e3)));
            s += dppf<0x108>(s); s += dppf<0x104>(s);
            s += dppf<0x102>(s); s += dppf<0x101>(s);
            q += dppf<0x108>(q); q += dppf<0x104>(q);
            q += dppf<0x102>(q); q += dppf<0x101>(q);
            #define MMERGE(C) { float m2 = dppf<C>(m); int a2 = dppi<C>(a); \
                bool bt = (m2 > m) || (m2 == m && a2 < a); \
                m = bt ? m2 : m; a = bt ? a2 : a; }
            MMERGE(0x108) MMERGE(0x104) MMERGE(0x102) MMERGE(0x101)
            #undef MMERGE
            if (c16 == 0) {
                int grow = m0 + arow0 + (i << 4) + (rg << 2) + reg;
                pstats[(size_t)((blockIdx.x << 1) + (w & 1)) * 8192 + grow] =
                    make_float4(m, s, q, __int_as_float(a));
            }
        }
    }
}

// ---------------- final finalize: merge t=5 panels, close outputs -----------
__global__ __launch_bounds__(64) void finalize_kernel(
    const float4* __restrict__ pstats, float* __restrict__ out_seq,
    float* __restrict__ out_sel, float* __restrict__ out_ent,
    float* __restrict__ out_ml)
{
    const int row = blockIdx.x * 64 + threadIdx.x;
    float M = -INFINITY, S = 0.f, Q = 0.f; int A = 0;
    #pragma unroll 8
    for (int p = 0; p < 64; ++p) {
        float4 pp = pstats[(size_t)p * 8192 + row];
        S += pp.y; Q += pp.z;
        int a2 = __float_as_int(pp.w);
        if (pp.x > M || (pp.x == M && a2 < A)) { M = pp.x; A = a2; }
    }
    float lse = __logf(S);
    float sel = M - lse;
    float ent = lse - Q / S;
    out_seq[(size_t)row * 6 + 5] = (float)A;
    out_sel[(size_t)row * 6 + 5] = sel;
    out_ent[row] = (out_ent[row] + ent) * (1.0f / 6.0f);
    out_ml[row] = 6.0f;
}

// ---------------------------------------------------------------------------
extern "C" void kernel_launch(void* const* d_in, const int* in_sizes, int n_in,
                              void* d_out, int out_size, void* d_ws, size_t ws_size,
                              hipStream_t stream) {
    const float* vis  = (const float*)d_in[0];
    const float* Wv   = (const float*)d_in[1];
    const float* bv   = (const float*)d_in[2];
    const float* gk   = (const float*)d_in[3];
    const float* grk  = (const float*)d_in[4];
    const float* bin  = (const float*)d_in[5];
    const float* brec = (const float*)d_in[6];
    const float* Wo   = (const float*)d_in[7];
    const float* bo   = (const float*)d_in[8];
    const float* emb  = (const float*)d_in[9];

    float* out = (float*)d_out;
    float* out_seq = out;                 // (8192, 6)
    float* out_sel = out + 49152;         // (8192, 6)
    float* out_ent = out + 98304;         // (8192,)
    float* out_ml  = out + 106496;        // (8192,)
    float* out_ht  = out + 114688;        // (8192, 256)

    char* ws = (char*)d_ws;
    float*          ph     = (float*)(ws);                       // 8 MB
    float*          hm     = (float*)(ws + 8388608);             // 24 MB
    unsigned short* vis0   = (unsigned short*)(ws + 8388608);    // 8 MB (overlay hm; dead before K2)
    unsigned short* vis1   = (unsigned short*)(ws + 16777216);   // 8 MB (overlay hm)
    unsigned short* h0     = (unsigned short*)(ws + 33554432);   // 4 MB
    unsigned short* h1     = (unsigned short*)(ws + 37748736);   // 4 MB
    unsigned short* w0     = (unsigned short*)(ws + 41943040);   // 2 MB
    unsigned short* w1     = (unsigned short*)(ws + 44040192);   // 2 MB
    float4*         pstats = (float4*)(ws + 46137344);           // 8 MB
    unsigned short* ph0    = (unsigned short*)(ws + 46137344);   // 4 MB (overlay pstats; dead before first logits)
    unsigned short* ph1    = (unsigned short*)(ws + 50331648);   // 4 MB (overlay pstats)
    unsigned short* wv0    = (unsigned short*)(ws + 54558720);   // 256 KB
    unsigned short* wv1    = (unsigned short*)(ws + 54820864);   // 256 KB
    unsigned short* g0     = (unsigned short*)(ws + 55083008);   // 384 KB
    unsigned short* g1     = (unsigned short*)(ws + 55476224);   // 384 KB

    // one-time weight preps (loop-invariant)
    trans_split<<<dim3(64, 4), 256, 0, stream>>>(Wo, w0, w1, 4096, 256);
    trans_split<<<dim3(4, 8), 256, 0, stream>>>(Wv, wv0, wv1, 256, 512);
    trans_split<<<dim3(12, 4), 256, 0, stream>>>(grk, g0, g1, 768, 256);
    split_ew<<<4096, 256, 0, stream>>>(vis, vis0, vis1, 1048576);

    // K1: prev_hidden = vis @ Wv + bv (epilogue also emits ph0/ph1 splits)
    mfma_gemm<512, true><<<dim3(4, 128), 256, 0, stream>>>(
        vis0, vis1, wv0, wv1, bv, ph, 256, ph0, ph1);
    // K2: hm = prev_hidden @ grk + brec (loop-invariant)
    mfma_gemm<256, false><<<dim3(12, 128), 256, 0, stream>>>(
        ph0, ph1, g0, g1, brec, hm, 768, nullptr, nullptr);

    for (int t = 0; t < 6; ++t) {
        gru_fused<<<1024, 256, 0, stream>>>(pstats, emb, gk, bin, hm, ph,
                                            h0, h1,
                                            (t == 5) ? out_ht : nullptr,
                                            out_seq, out_sel, out_ent, t);
        logits_mfma<<<dim3(32, 64), 256, 0, stream>>>(h0, h1, w0, w1, bo, pstats);
    }
    finalize_kernel<<<128, 64, 0, stream>>>(pstats, out_seq, out_sel,
                                            out_ent, out_ml);
}

// Round 14
// 520.547 us; speedup vs baseline: 1.2669x; 1.0699x over previous
//
#include <hip/hip_runtime.h>
#include <hip/hip_fp16.h>
#include <math.h>

// ---------------------------------------------------------------------------
// Sender model, MI355X, round 14 = R13 (best-known) + embgk table.
// All GEMMs on fp16x2 (Markidis) MFMA: 3 products, fp32 accumulate.
// NEW: xm = emb[sym] @ gk == (emb @ gk)[sym]  -- the per-step x-GEMM in
// gru_fused is a gather from the loop-invariant table embgk (4096x768 fp32,
// precomputed once via the same MFMA path). Removes 1536 VALU FMA + gk loads
// per thread per step. Guarded by ws_size (fallback = R13 path).
// logits kernel untouched (R8 form, proven 67us; 5 structural variants all
// regressed -- see R9-R12 history).
// ---------------------------------------------------------------------------

typedef __attribute__((ext_vector_type(8))) _Float16 half8v;  // 16 B
typedef __attribute__((ext_vector_type(4))) float f32x4;

// slot swizzle; row stride 64 B
__device__ __forceinline__ int lds_off(int row, int slot) {
    return (row << 6) + ((slot ^ (row & 3) ^ ((row >> 2) & 3)) << 4);
}

__device__ __forceinline__ void gld_lds16(const void* src, void* dst) {
    __builtin_amdgcn_global_load_lds(
        (const __attribute__((address_space(1))) void*)src,
        (__attribute__((address_space(3))) void*)dst, 16, 0, 0);
}

template<int C>
__device__ __forceinline__ float dppf(float x) {
    return __builtin_bit_cast(float, __builtin_amdgcn_update_dpp(
        __builtin_bit_cast(int, x), __builtin_bit_cast(int, x), C, 0xF, 0xF, false));
}
template<int C>
__device__ __forceinline__ int dppi(int x) {
    return __builtin_amdgcn_update_dpp(x, x, C, 0xF, 0xF, false);
}

__device__ __forceinline__ void f16split(float v, unsigned short& u0,
                                         unsigned short& u1) {
    __half a = __float2half(v);            // RTNE
    float f = __half2float(a);
    __half b = __float2half(v - f);
    u0 = __half_as_ushort(a);
    u1 = __half_as_ushort(b);
}

__device__ __forceinline__ float fast_tanh(float x) {
    float t = __expf(-2.0f * fabsf(x));    // t in (0,1], no overflow
    float th = (1.0f - t) / (1.0f + t);
    return copysignf(th, x);
}

// ---------------- elementwise fp16x2 split (vis, emb) -----------------------
__global__ __launch_bounds__(256) void split_ew(
    const float* __restrict__ in, unsigned short* __restrict__ o0,
    unsigned short* __restrict__ o1, int n4)
{
    int i = blockIdx.x * 256 + threadIdx.x;
    if (i >= n4) return;
    float4 v = *(const float4*)&in[(size_t)i * 4];
    unsigned short a[4], b[4];
    f16split(v.x, a[0], b[0]); f16split(v.y, a[1], b[1]);
    f16split(v.z, a[2], b[2]); f16split(v.w, a[3], b[3]);
    *(uint2*)&o0[(size_t)i * 4] = *(uint2*)a;
    *(uint2*)&o1[(size_t)i * 4] = *(uint2*)b;
}

// ---------------- W[K][N] -> [n][k] fp16x2 splits (Wo, Wv, grk, gk) ---------
__global__ __launch_bounds__(256) void trans_split(
    const float* __restrict__ W, unsigned short* __restrict__ o0,
    unsigned short* __restrict__ o1, int N, int K)
{
    __shared__ float Ts[64][65];
    const int tid = threadIdx.x;
    const int n0 = blockIdx.x * 64, k0 = blockIdx.y * 64;
    const int ty = tid >> 2, tx = tid & 3;
    #pragma unroll
    for (int q = 0; q < 4; ++q) {
        float4 v = *(const float4*)&W[(size_t)(k0 + ty) * N + n0 + tx * 16 + q * 4];
        Ts[ty][tx * 16 + q * 4 + 0] = v.x; Ts[ty][tx * 16 + q * 4 + 1] = v.y;
        Ts[ty][tx * 16 + q * 4 + 2] = v.z; Ts[ty][tx * 16 + q * 4 + 3] = v.w;
    }
    __syncthreads();
    #pragma unroll
    for (int ii = 0; ii < 2; ++ii) {
        int item = tid + (ii << 8);          // 0..511
        int n = item >> 3, g = item & 7;     // n 0..63, k-group 0..7
        unsigned short u0[8], u1[8];
        #pragma unroll
        for (int e = 0; e < 8; ++e)
            f16split(Ts[g * 8 + e][n], u0[e], u1[e]);
        size_t base = (size_t)(n0 + n) * K + k0 + g * 8;
        *(uint4*)&o0[base] = *(uint4*)u0;
        *(uint4*)&o1[base] = *(uint4*)u1;
    }
}

// ---------------- fp16x2 MFMA GEMM, 64x64 tile (K1, K2, embgk) --------------
// 4 waves (2x2), wave tile 32x32 = 2x2 frags of 16x16x32 f16, 3 products.
// Single-buffer 16 KB LDS. SPLIT: also emit fp16x2 split of C (K1 -> ph0/ph1).
// bias may be nullptr (embgk).
template<int KTOT, bool SPLIT>
__global__ __launch_bounds__(256) void mfma_gemm(
    const unsigned short* __restrict__ a0s, const unsigned short* __restrict__ a1s,
    const unsigned short* __restrict__ b0s, const unsigned short* __restrict__ b1s,
    const float* __restrict__ bias, float* __restrict__ C, int ldc,
    unsigned short* __restrict__ s0, unsigned short* __restrict__ s1)
{
    __shared__ char lds[16384];
    const int tid = threadIdx.x;
    const int w = tid >> 6, lane = tid & 63;
    const int c16 = lane & 15, rg = lane >> 4;
    const int m0 = blockIdx.y << 6, n0 = blockIdx.x << 6;
    const int arow0 = (w >> 1) << 5, brow0 = (w & 1) << 5;

    const unsigned short* segsrc = (w == 0) ? a0s : (w == 1) ? a1s
                                 : (w == 2) ? b0s : b1s;
    const int segrow0 = (w < 2) ? m0 : n0;

    f32x4 acc[2][2] = {};

    for (int t = 0; t < KTOT / 32; ++t) {
        const int k0 = t << 5;
        #pragma unroll
        for (int q = 0; q < 4; ++q) {
            int row = (q << 4) + (lane >> 2);
            int slot = (lane & 3) ^ (row & 3) ^ ((row >> 2) & 3);
            gld_lds16(segsrc + (size_t)(segrow0 + row) * KTOT + k0 + (slot << 3),
                      &lds[(w << 12) + (q << 10)]);
        }
        asm volatile("s_waitcnt vmcnt(0)" ::: "memory");
        __syncthreads();
        half8v afr[2][2], bfr[2][2];
        #pragma unroll
        for (int i = 0; i < 2; ++i) {
            int oa = lds_off(arow0 + (i << 4) + c16, rg);
            afr[i][0] = *(half8v*)&lds[oa];
            afr[i][1] = *(half8v*)&lds[4096 + oa];
            int ob = lds_off(brow0 + (i << 4) + c16, rg);
            bfr[i][0] = *(half8v*)&lds[8192 + ob];
            bfr[i][1] = *(half8v*)&lds[12288 + ob];
        }
        #pragma unroll
        for (int i = 0; i < 2; ++i)
            #pragma unroll
            for (int j = 0; j < 2; ++j) {
                f32x4 c = acc[i][j];
                c = __builtin_amdgcn_mfma_f32_16x16x32_f16(afr[i][0], bfr[j][0], c, 0, 0, 0);
                c = __builtin_amdgcn_mfma_f32_16x16x32_f16(afr[i][1], bfr[j][0], c, 0, 0, 0);
                c = __builtin_amdgcn_mfma_f32_16x16x32_f16(afr[i][0], bfr[j][1], c, 0, 0, 0);
                acc[i][j] = c;
            }
        __syncthreads();
    }

    #pragma unroll
    for (int j = 0; j < 2; ++j) {
        int col = n0 + brow0 + (j << 4) + c16;
        float bb = bias ? bias[col] : 0.0f;
        #pragma unroll
        for (int i = 0; i < 2; ++i)
            #pragma unroll
            for (int reg = 0; reg < 4; ++reg) {
                int row = m0 + arow0 + (i << 4) + (rg << 2) + reg;
                float v = acc[i][j][reg] + bb;
                C[(size_t)row * ldc + col] = v;
                if (SPLIT) {
                    unsigned short u0, u1;
                    f16split(v, u0, u1);
                    s0[(size_t)row * ldc + col] = u0;
                    s1[(size_t)row * ldc + col] = u1;
                }
            }
    }
}

// ---------------- gru_fused: merge(t-1) + xm gather/GEMM + GRU + h split ----
// 8 rows/block. t>0: merge step t-1's 64 pstats panels for these rows,
// write outputs for t-1; xm from embgk table (or fallback x@gk path).
__global__ __launch_bounds__(256) void gru_fused(
    const float4* __restrict__ pstats, const float* __restrict__ emb,
    const float* __restrict__ embgk,
    const float* __restrict__ gk, const float* __restrict__ b_in,
    const float* __restrict__ hm, const float* __restrict__ ph,
    unsigned short* __restrict__ h0, unsigned short* __restrict__ h1,
    float* __restrict__ ht_out, float* __restrict__ out_seq,
    float* __restrict__ out_sel, float* __restrict__ out_ent, int t)
{
    __shared__ float xsT[64][8];
    __shared__ int syms_lds[8];
    const int tid = threadIdx.x;
    const int row0 = blockIdx.x * 8;
    float az[8], ar[8], ah[8];
    const float bz = b_in[tid], br = b_in[256 + tid], bh = b_in[512 + tid];
    #pragma unroll
    for (int r = 0; r < 8; ++r) { az[r] = bz; ar[r] = br; ah[r] = bh; }

    if (t > 0) {
        const int r = tid >> 5, p = tid & 31;
        const int row = row0 + r;
        float4 pa = pstats[(size_t)p * 8192 + row];
        float4 pb = pstats[(size_t)(p + 32) * 8192 + row];
        float M = pa.x, S = pa.y + pb.y, Q = pa.z + pb.z;
        int A = __float_as_int(pa.w);
        { int a2 = __float_as_int(pb.w);
          if (pb.x > M || (pb.x == M && a2 < A)) { M = pb.x; A = a2; } }
        #pragma unroll
        for (int off = 1; off < 32; off <<= 1) {
            float m2 = __shfl_xor(M, off);
            float s2 = __shfl_xor(S, off);
            float q2 = __shfl_xor(Q, off);
            int   a2 = __shfl_xor(A, off);
            S += s2; Q += q2;
            if (m2 > M || (m2 == M && a2 < A)) { M = m2; A = a2; }
        }
        if (p == 0) {
            float lse = __logf(S);
            float sel = M - lse;
            float ent = lse - Q / S;
            out_seq[(size_t)row * 6 + (t - 1)] = (float)A;
            out_sel[(size_t)row * 6 + (t - 1)] = sel;
            float ea = (t == 1) ? ent : (out_ent[row] + ent);
            out_ent[row] = ea;
            syms_lds[r] = A;
        }
        __syncthreads();
        if (embgk) {
            // xm = (emb @ gk)[sym] -- 24 coalesced loads, no GEMM
            #pragma unroll
            for (int r2 = 0; r2 < 8; ++r2) {
                size_t b = (size_t)syms_lds[r2] * 768 + tid;
                az[r2] += embgk[b];
                ar[r2] += embgk[b + 256];
                ah[r2] += embgk[b + 512];
            }
        } else {
            // fallback: gather emb + x @ gk in VALU (R13 path)
            for (int l = tid; l < 512; l += 256) {
                int r2 = l >> 6, e = l & 63;
                xsT[e][r2] = emb[(size_t)syms_lds[r2] * 64 + e];
            }
            __syncthreads();
            #pragma unroll 4
            for (int e = 0; e < 64; ++e) {
                float kz  = gk[e * 768 + tid];
                float kr_ = gk[e * 768 + 256 + tid];
                float kh  = gk[e * 768 + 512 + tid];
                float4 x0 = *(float4*)&xsT[e][0];
                float4 x1 = *(float4*)&xsT[e][4];
                float xv[8] = {x0.x, x0.y, x0.z, x0.w, x1.x, x1.y, x1.z, x1.w};
                #pragma unroll
                for (int r2 = 0; r2 < 8; ++r2) {
                    az[r2] = fmaf(xv[r2], kz, az[r2]);
                    ar[r2] = fmaf(xv[r2], kr_, ar[r2]);
                    ah[r2] = fmaf(xv[r2], kh, ah[r2]);
                }
            }
        }
    }
    #pragma unroll
    for (int r = 0; r < 8; ++r) {
        const int row = row0 + r;
        float hz  = hm[(size_t)row * 768 + tid];
        float hr  = hm[(size_t)row * 768 + 256 + tid];
        float hh  = hm[(size_t)row * 768 + 512 + tid];
        float phv = ph[(size_t)row * 256 + tid];
        float z  = 1.0f / (1.0f + __expf(-(az[r] + hz)));
        float rr = 1.0f / (1.0f + __expf(-(ar[r] + hr)));
        float ht = fast_tanh(ah[r] + rr * hh);
        float hv = z * phv + (1.0f - z) * ht;
        size_t idx = (size_t)row * 256 + tid;
        unsigned short u0, u1;
        f16split(hv, u0, u1);
        h0[idx] = u0; h1[idx] = u1;
        if (ht_out) ht_out[idx] = hv;
    }
}

// ---------------- logits: 128x128 fp16x2 MFMA, single-buf 32 KB (R8) --------
__global__ __launch_bounds__(256, 3) void logits_mfma(
    const unsigned short* __restrict__ h0, const unsigned short* __restrict__ h1,
    const unsigned short* __restrict__ w0, const unsigned short* __restrict__ w1,
    const float* __restrict__ bo, float4* __restrict__ pstats)
{
    __shared__ char lds[32768];
    const int tid = threadIdx.x;
    const int w = tid >> 6, lane = tid & 63;
    const int c16 = lane & 15, rg = lane >> 4;
    const int m0 = blockIdx.y << 7, n0 = blockIdx.x << 7;
    const int arow0 = (w >> 1) << 6, brow0 = (w & 1) << 6;

    const unsigned short* segsrc = (w == 0) ? h0 : (w == 1) ? h1
                                 : (w == 2) ? w0 : w1;
    const int segrow0 = (w < 2) ? m0 : n0;

    f32x4 acc[4][4] = {};

    for (int t = 0; t < 8; ++t) {
        const int k0 = t << 5;
        #pragma unroll
        for (int q = 0; q < 8; ++q) {          // stage this K-step (own segment)
            int row = (q << 4) + (lane >> 2);
            int slot = (lane & 3) ^ (row & 3) ^ ((row >> 2) & 3);
            gld_lds16(segsrc + (size_t)(segrow0 + row) * 256 + k0 + (slot << 3),
                      &lds[(w << 13) + (q << 10)]);
        }
        asm volatile("s_waitcnt vmcnt(0)" ::: "memory");
        __syncthreads();
        half8v afr[4][2];
        #pragma unroll
        for (int i = 0; i < 4; ++i) {
            int o = lds_off(arow0 + (i << 4) + c16, rg);
            afr[i][0] = *(half8v*)&lds[o];
            afr[i][1] = *(half8v*)&lds[8192 + o];
        }
        #pragma unroll
        for (int j = 0; j < 4; ++j) {
            int o = lds_off(brow0 + (j << 4) + c16, rg);
            half8v b0 = *(half8v*)&lds[16384 + o];
            half8v b1 = *(half8v*)&lds[24576 + o];
            #pragma unroll
            for (int i = 0; i < 4; ++i) {
                f32x4 c = acc[i][j];
                c = __builtin_amdgcn_mfma_f32_16x16x32_f16(afr[i][0], b0, c, 0, 0, 0);
                c = __builtin_amdgcn_mfma_f32_16x16x32_f16(afr[i][1], b0, c, 0, 0, 0);
                c = __builtin_amdgcn_mfma_f32_16x16x32_f16(afr[i][0], b1, c, 0, 0, 0);
                acc[i][j] = c;
            }
        }
        __syncthreads();
    }

    // epilogue: raw softmax stats + DPP reductions across the 16 c16 lanes.
    const int wn0 = n0 + brow0;
    float bov[4];
    #pragma unroll
    for (int j = 0; j < 4; ++j) bov[j] = bo[wn0 + j * 16 + c16];
    #pragma unroll
    for (int i = 0; i < 4; ++i) {
        #pragma unroll
        for (int reg = 0; reg < 4; ++reg) {
            float l0 = acc[i][0][reg] + bov[0];
            float l1 = acc[i][1][reg] + bov[1];
            float l2 = acc[i][2][reg] + bov[2];
            float l3 = acc[i][3][reg] + bov[3];
            float m = l0; int a = wn0 + c16;
            if (l1 > m) { m = l1; a = wn0 + 16 + c16; }
            if (l2 > m) { m = l2; a = wn0 + 32 + c16; }
            if (l3 > m) { m = l3; a = wn0 + 48 + c16; }
            float e0 = __expf(l0), e1 = __expf(l1), e2 = __expf(l2), e3 = __expf(l3);
            float s = (e0 + e1) + (e2 + e3);
            float q = fmaf(l0, e0, fmaf(l1, e1, fmaf(l2, e2, l3 * e3)));
            s += dppf<0x108>(s); s += dppf<0x104>(s);
            s += dppf<0x102>(s); s += dppf<0x101>(s);
            q += dppf<0x108>(q); q += dppf<0x104>(q);
            q += dppf<0x102>(q); q += dppf<0x101>(q);
            #define MMERGE(C) { float m2 = dppf<C>(m); int a2 = dppi<C>(a); \
                bool bt = (m2 > m) || (m2 == m && a2 < a); \
                m = bt ? m2 : m; a = bt ? a2 : a; }
            MMERGE(0x108) MMERGE(0x104) MMERGE(0x102) MMERGE(0x101)
            #undef MMERGE
            if (c16 == 0) {
                int grow = m0 + arow0 + (i << 4) + (rg << 2) + reg;
                pstats[(size_t)((blockIdx.x << 1) + (w & 1)) * 8192 + grow] =
                    make_float4(m, s, q, __int_as_float(a));
            }
        }
    }
}

// ---------------- final finalize: merge t=5 panels, close outputs -----------
__global__ __launch_bounds__(64) void finalize_kernel(
    const float4* __restrict__ pstats, float* __restrict__ out_seq,
    float* __restrict__ out_sel, float* __restrict__ out_ent,
    float* __restrict__ out_ml)
{
    const int row = blockIdx.x * 64 + threadIdx.x;
    float M = -INFINITY, S = 0.f, Q = 0.f; int A = 0;
    #pragma unroll 8
    for (int p = 0; p < 64; ++p) {
        float4 pp = pstats[(size_t)p * 8192 + row];
        S += pp.y; Q += pp.z;
        int a2 = __float_as_int(pp.w);
        if (pp.x > M || (pp.x == M && a2 < A)) { M = pp.x; A = a2; }
    }
    float lse = __logf(S);
    float sel = M - lse;
    float ent = lse - Q / S;
    out_seq[(size_t)row * 6 + 5] = (float)A;
    out_sel[(size_t)row * 6 + 5] = sel;
    out_ent[row] = (out_ent[row] + ent) * (1.0f / 6.0f);
    out_ml[row] = 6.0f;
}

// ---------------------------------------------------------------------------
extern "C" void kernel_launch(void* const* d_in, const int* in_sizes, int n_in,
                              void* d_out, int out_size, void* d_ws, size_t ws_size,
                              hipStream_t stream) {
    const float* vis  = (const float*)d_in[0];
    const float* Wv   = (const float*)d_in[1];
    const float* bv   = (const float*)d_in[2];
    const float* gk   = (const float*)d_in[3];
    const float* grk  = (const float*)d_in[4];
    const float* bin  = (const float*)d_in[5];
    const float* brec = (const float*)d_in[6];
    const float* Wo   = (const float*)d_in[7];
    const float* bo   = (const float*)d_in[8];
    const float* emb  = (const float*)d_in[9];

    float* out = (float*)d_out;
    float* out_seq = out;                 // (8192, 6)
    float* out_sel = out + 49152;         // (8192, 6)
    float* out_ent = out + 98304;         // (8192,)
    float* out_ml  = out + 106496;        // (8192,)
    float* out_ht  = out + 114688;        // (8192, 256)

    char* ws = (char*)d_ws;
    float*          ph     = (float*)(ws);                       // 8 MB
    float*          hm     = (float*)(ws + 8388608);             // 24 MB
    unsigned short* vis0   = (unsigned short*)(ws + 8388608);    // 8 MB (overlay hm; dead before K2)
    unsigned short* vis1   = (unsigned short*)(ws + 16777216);   // 8 MB (overlay hm)
    unsigned short* h0     = (unsigned short*)(ws + 33554432);   // 4 MB
    unsigned short* h1     = (unsigned short*)(ws + 37748736);   // 4 MB
    unsigned short* w0     = (unsigned short*)(ws + 41943040);   // 2 MB
    unsigned short* w1     = (unsigned short*)(ws + 44040192);   // 2 MB
    float4*         pstats = (float4*)(ws + 46137344);           // 8 MB
    unsigned short* ph0    = (unsigned short*)(ws + 46137344);   // 4 MB (overlay pstats; dead before first logits)
    unsigned short* ph1    = (unsigned short*)(ws + 50331648);   // 4 MB (overlay pstats)
    unsigned short* wv0    = (unsigned short*)(ws + 54558720);   // 256 KB
    unsigned short* wv1    = (unsigned short*)(ws + 54820864);   // 256 KB
    unsigned short* g0     = (unsigned short*)(ws + 55083008);   // 384 KB
    unsigned short* g1     = (unsigned short*)(ws + 55476224);   // 384 KB
    float*          embgk  = (float*)(ws + 55869440);            // 12 MB (table)
    unsigned short* gk0    = (unsigned short*)(ws + 68452352);   // 96 KB
    unsigned short* gk1    = (unsigned short*)(ws + 68550656);   // 96 KB -> ends 68648960

    const bool use_tbl = (ws_size >= 68648960ULL);
    // emb splits (one-time) reuse h0/h1 (free until gru step 0 writes them)
    unsigned short* emb0 = h0;
    unsigned short* emb1 = h1;

    // one-time weight preps (loop-invariant)
    trans_split<<<dim3(64, 4), 256, 0, stream>>>(Wo, w0, w1, 4096, 256);
    trans_split<<<dim3(4, 8), 256, 0, stream>>>(Wv, wv0, wv1, 256, 512);
    trans_split<<<dim3(12, 4), 256, 0, stream>>>(grk, g0, g1, 768, 256);
    split_ew<<<4096, 256, 0, stream>>>(vis, vis0, vis1, 1048576);
    if (use_tbl) {
        trans_split<<<dim3(12, 1), 256, 0, stream>>>(gk, gk0, gk1, 768, 64);
        split_ew<<<256, 256, 0, stream>>>(emb, emb0, emb1, 65536);
    }

    // K1: prev_hidden = vis @ Wv + bv (epilogue also emits ph0/ph1 splits)
    mfma_gemm<512, true><<<dim3(4, 128), 256, 0, stream>>>(
        vis0, vis1, wv0, wv1, bv, ph, 256, ph0, ph1);
    // K2: hm = prev_hidden @ grk + brec (loop-invariant)
    mfma_gemm<256, false><<<dim3(12, 128), 256, 0, stream>>>(
        ph0, ph1, g0, g1, brec, hm, 768, nullptr, nullptr);
    // embgk = emb @ gk (loop-invariant table)
    if (use_tbl)
        mfma_gemm<64, false><<<dim3(12, 64), 256, 0, stream>>>(
            emb0, emb1, gk0, gk1, nullptr, embgk, 768, nullptr, nullptr);

    for (int t = 0; t < 6; ++t) {
        gru_fused<<<1024, 256, 0, stream>>>(pstats, emb,
                                            use_tbl ? embgk : nullptr,
                                            gk, bin, hm, ph, h0, h1,
                                            (t == 5) ? out_ht : nullptr,
                                            out_seq, out_sel, out_ent, t);
        logits_mfma<<<dim3(32, 64), 256, 0, stream>>>(h0, h1, w0, w1, bo, pstats);
    }
    finalize_kernel<<<128, 64, 0, stream>>>(pstats, out_seq, out_sel,
                                            out_ent, out_ml);
}